// Round 8
// baseline (145.970 us; speedup 1.0000x reference)
//
#include <hip/hip_runtime.h>
#include <hip/hip_bf16.h>
#include <math.h>

typedef __attribute__((ext_vector_type(8))) _Float16 half8;   // 8 x f16 (4 VGPR)
typedef __attribute__((ext_vector_type(2))) _Float16 half2v;
typedef __attribute__((ext_vector_type(4))) float f32x4;      // MFMA acc

#define OBS_X 40.0f
#define OBS_Y 15.0f
#define RADIUS 6.0f
#define TPW 8       // tiles (16 rows each) per wave; multiple of 4
#define GRID 1024   // 1024 blocks * 4 waves * TPW * 16 rows = 524288

__device__ __forceinline__ half2v pkrtz(float a, float b) {
    return __builtin_bit_cast(half2v, __builtin_amdgcn_cvt_pkrtz(a, b));
}

// fp16 hi/lo split of 8 floats (RNE casts — must match everywhere)
__device__ __forceinline__ void split8(const float* v, half8& hi, half8& lo) {
#pragma unroll
    for (int j = 0; j < 8; ++j) {
        _Float16 h = (_Float16)v[j];
        hi[j] = h;
        lo[j] = (_Float16)(v[j] - (float)h);
    }
}

// Opaque register pin
__device__ __forceinline__ void pin(half8& v) {
    f32x4 t = __builtin_bit_cast(f32x4, v);
    asm volatile("" : "+v"(t));
    v = __builtin_bit_cast(half8, t);
}

// LDS map (bytes):
//   [0,32768)       4 per-wave h1 hi/lo planes (XOR-swizzled), 8192 each
//   [32768,49152)   w2lo frags, block-shared: [(t*4+kc)*64 + lane]*16
//   [49152,51200)   w1c_h [128 rows][16B]: w1 hi cols0-4, b1 hi col5, 0 pad
//   [51200,53248)   w1c_l (lo parts)
//   [53248,53264)   16B zero row (fc1 A-frag for lane group g==3)
__global__ __launch_bounds__(256, 3) void barriernet_fused(
    const float* __restrict__ x,
    const float* __restrict__ mean_, const float* __restrict__ std_,
    const float* __restrict__ w1,  const float* __restrict__ b1,
    const float* __restrict__ w21, const float* __restrict__ b21,
    const float* __restrict__ w22, const float* __restrict__ b22,
    const float* __restrict__ w31, const float* __restrict__ b31,
    const float* __restrict__ w32, const float* __restrict__ b32,
    float* __restrict__ out)
{
    __shared__ unsigned char smem[53264];
    const int tid  = threadIdx.x;
    const int lane = tid & 63;
    const int wv   = tid >> 6;
    const int r16  = lane & 15;     // batch row within tile / MFMA col
    const int g    = lane >> 4;     // lane group 0..3
    unsigned char* h1hi = smem + wv * 8192;             // [16 rows][128 feats] f16
    unsigned char* h1lo = h1hi + 4096;
    const unsigned swz = ((unsigned)(r16 & 7)) << 4;
    const int slot = blockIdx.x * 4 + wv;               // 0..4095

    // ---- one-time: w1c frags in LDS (threads 0-127) ----
    if (tid < 128) {
        float v[8];
#pragma unroll
        for (int j = 0; j < 5; ++j) v[j] = w1[tid * 5 + j];
        v[5] = b1[tid];
        v[6] = 0.f; v[7] = 0.f;
        half8 hi, lo;
        split8(v, hi, lo);
        *(half8*)(smem + 49152 + tid * 16) = hi;
        *(half8*)(smem + 51200 + tid * 16) = lo;
    }
    if (tid == 128) {
        half8 z = {0,0,0,0,0,0,0,0};
        *(half8*)(smem + 53248) = z;
    }

    // ---- one-time: cooperative w2lo build into block-shared LDS ----
#pragma unroll
    for (int m = 0; m < 4; ++m) {
        const int s = tid * 4 + m;          // 0..1023 = frag*64 + lane
        const int f = s >> 6, l = s & 63;
        const int r = 16 * (f >> 2) + (l & 15);
        const int k0 = (f & 3) * 32 + (l >> 4) * 8;
        const float* src = (r < 32) ? (w21 + r * 128 + k0) : (w22 + (r - 32) * 128 + k0);
        const float4 f0 = *(const float4*)(src);
        const float4 f1 = *(const float4*)(src + 4);
        float v[8] = {f0.x, f0.y, f0.z, f0.w, f1.x, f1.y, f1.z, f1.w};
        half8 hi, lo;
        split8(v, hi, lo);
        *(half8*)(smem + 32768 + s * 16) = lo;
    }

    // ---- one-time: per-wave w2hi gather into pinned registers (64 VGPR) ----
    half8 w2h[4][4];
#pragma unroll
    for (int t = 0; t < 4; ++t) {
        const int r = 16 * t + r16;
        const float* src = (r < 32) ? (w21 + r * 128) : (w22 + (r - 32) * 128);
#pragma unroll
        for (int kc = 0; kc < 4; ++kc) {
            const float4 f0 = *(const float4*)(src + kc * 32 + g * 8);
            const float4 f1 = *(const float4*)(src + kc * 32 + g * 8 + 4);
            float v[8] = {f0.x, f0.y, f0.z, f0.w, f1.x, f1.y, f1.z, f1.w};
#pragma unroll
            for (int j = 0; j < 8; ++j) w2h[t][kc][j] = (_Float16)v[j];
            pin(w2h[t][kc]);
        }
    }

    __syncthreads();    // LDS weight regions ready; only barrier in the kernel

    // hoisted uniform scalars (SGPR)
    const float m0 = mean_[0], m1 = mean_[1], m2 = mean_[2], m3 = mean_[3];
    const float sd0 = std_[0], sd1 = std_[1], sd2 = std_[2], sd3 = std_[3];
    const float bb31_0 = b31[0], bb31_1 = b31[1], bb32_0 = b32[0], bb32_1 = b32[1];

    // fc1 A-frag LDS base (g<2: hi rows, g==2: lo rows, g==3: zero row)
    const unsigned awbase = (g < 2) ? 49152u : ((g == 2) ? 51200u : 53248u);
    const unsigned awstep = (g == 3) ? 0u : 16u;
    const unsigned w2lbase = 32768u + (unsigned)lane * 16u;

    // ---- x prefetch for tile 0 (all lanes load row r16: quad-broadcast) ----
    float xa0, xa1, xa2, xa3, xa4;
    {
        const float* xr = x + (size_t)(slot * TPW * 16 + r16) * 5;
        xa0 = xr[0]; xa1 = xr[1]; xa2 = xr[2]; xa3 = xr[3]; xa4 = xr[4];
    }

    float P0 = 0.f, P1 = 0.f, P2 = 0.f, P3 = 0.f;   // deferred head values (per-lane row)

#pragma unroll 1
    for (int it = 0; it < TPW; ++it) {
        const int rowbase = (slot * TPW + it) * 16;

        // ---- build fc1 concat B-frag: [xh(5),1 | xl(5),0 | xh(5),1 | 0] over k-groups ----
        half8 bx = {0,0,0,0,0,0,0,0};
        {
            float xs[5] = {xa0, xa1, xa2, xa3, xa4};
            const bool useL = (g == 1), useZ = (g == 3);
#pragma unroll
            for (int j = 0; j < 5; ++j) {
                _Float16 h = (_Float16)xs[j];
                _Float16 l = (_Float16)(xs[j] - (float)h);
                bx[j] = useZ ? (_Float16)0.f : (useL ? l : h);
            }
            bx[5] = (useZ || useL) ? (_Float16)0.f : (_Float16)1.0f;
        }

        // prefetch next tile's x
        if (it + 1 < TPW) {
            const float* xr = x + (size_t)(rowbase + 16 + r16) * 5;
            xa0 = xr[0]; xa1 = xr[1]; xa2 = xr[2]; xa3 = xr[3]; xa4 = xr[4];
        }

        // ---- fc1 = relu(W1'[x;1]^T): one MFMA per 16-feat block ----
#pragma unroll
        for (int t8 = 0; t8 < 8; ++t8) {
            const int fr = t8 * 16 + r16;
            const half8 aw = *(const half8*)(smem + awbase + (unsigned)fr * awstep);
            f32x4 acc = {0.f, 0.f, 0.f, 0.f};
            acc = __builtin_amdgcn_mfma_f32_16x16x32_f16(aw, bx, acc, 0, 0, 0);
            float v0 = fmaxf(acc[0], 0.f), v1 = fmaxf(acc[1], 0.f);
            float v2 = fmaxf(acc[2], 0.f), v3 = fmaxf(acc[3], 0.f);
            half2v hA = pkrtz(v0, v1);
            half2v hB = pkrtz(v2, v3);
            half2v lA = pkrtz(v0 - (float)hA[0], v1 - (float)hA[1]);
            half2v lB = pkrtz(v2 - (float)hB[0], v3 - (float)hB[1]);
            const unsigned off = ((unsigned)(32 * t8 + 8 * g)) ^ swz;
            uint2 ph; ph.x = __builtin_bit_cast(unsigned, hA); ph.y = __builtin_bit_cast(unsigned, hB);
            uint2 pl; pl.x = __builtin_bit_cast(unsigned, lA); pl.y = __builtin_bit_cast(unsigned, lB);
            *(uint2*)(h1hi + r16 * 256 + off) = ph;
            *(uint2*)(h1lo + r16 * 256 + off) = pl;
        }

        asm volatile("" ::: "memory");

        // ---- fc2cat: D[out 16t+4g+r][batch r16], A = w2hi(reg)/w2lo(LDS), fp16x3 ----
        half8 ah[4], al[4];
#pragma unroll
        for (int kc = 0; kc < 4; ++kc) {
            const unsigned off = ((unsigned)(kc * 64 + g * 16)) ^ swz;
            ah[kc] = *(const half8*)(h1hi + r16 * 256 + off);
            al[kc] = *(const half8*)(h1lo + r16 * 256 + off);
        }
        f32x4 acc2[4];
#pragma unroll
        for (int t = 0; t < 4; ++t) {
            const float4 bb2 = (t < 2) ? *(const float4*)(b21 + 16 * t + 4 * g)
                                       : *(const float4*)(b22 + 16 * (t - 2) + 4 * g);
            f32x4 a = {bb2.x, bb2.y, bb2.z, bb2.w};
#pragma unroll
            for (int kc = 0; kc < 4; ++kc) {
                const half8 wl = *(const half8*)(smem + w2lbase + (unsigned)((t * 4 + kc) << 10));
                a = __builtin_amdgcn_mfma_f32_16x16x32_f16(w2h[t][kc], al[kc], a, 0, 0, 0);
                a = __builtin_amdgcn_mfma_f32_16x16x32_f16(wl,         ah[kc], a, 0, 0, 0);
                a = __builtin_amdgcn_mfma_f32_16x16x32_f16(w2h[t][kc], ah[kc], a, 0, 0, 0);
            }
            acc2[t] = a;
        }

        asm volatile("" ::: "memory");

        // ---- heads: per-lane partials over outs {16t+4g+r}, butterfly over g ----
        const f32x4 wA0 = *(const f32x4*)(w31 + 4 * g);
        const f32x4 wA1 = *(const f32x4*)(w31 + 16 + 4 * g);
        const f32x4 wB0 = *(const f32x4*)(w31 + 32 + 4 * g);
        const f32x4 wB1 = *(const f32x4*)(w31 + 48 + 4 * g);
        const f32x4 wC0 = *(const f32x4*)(w32 + 4 * g);
        const f32x4 wC1 = *(const f32x4*)(w32 + 16 + 4 * g);
        const f32x4 wD0 = *(const f32x4*)(w32 + 32 + 4 * g);
        const f32x4 wD1 = *(const f32x4*)(w32 + 48 + 4 * g);
        float p0 = 0.f, p1 = 0.f, p2 = 0.f, p3 = 0.f;
#pragma unroll
        for (int r = 0; r < 4; ++r) {
            float v0 = fmaxf(acc2[0][r], 0.f), v1 = fmaxf(acc2[1][r], 0.f);
            float v2 = fmaxf(acc2[2][r], 0.f), v3 = fmaxf(acc2[3][r], 0.f);
            p0 += wA0[r] * v0 + wA1[r] * v1;
            p1 += wB0[r] * v0 + wB1[r] * v1;
            p2 += wC0[r] * v2 + wC1[r] * v3;
            p3 += wD0[r] * v2 + wD1[r] * v3;
        }
        p0 += __shfl_xor(p0, 16); p0 += __shfl_xor(p0, 32);
        p1 += __shfl_xor(p1, 16); p1 += __shfl_xor(p1, 32);
        p2 += __shfl_xor(p2, 16); p2 += __shfl_xor(p2, 32);
        p3 += __shfl_xor(p3, 16); p3 += __shfl_xor(p3, 32);

        // all 64 lanes now hold the reduced heads for batch col r16 of THIS tile.
        // lane L keeps the tile with index (it&3)==g, so after 4 tiles lane L owns row base64+L.
        {
            const bool sel = (g == (it & 3));
            P0 = sel ? p0 : P0;
            P1 = sel ? p1 : P1;
            P2 = sel ? p2 : P2;
            P3 = sel ? p3 : P3;
        }

        // ---- batched physics epilogue: every 4 tiles, all 64 lanes, own row ----
        if ((it & 3) == 3) {
            const int row = (slot * TPW + (it - 3)) * 16 + lane;
            const float* xr = x + (size_t)row * 5;
            const float e0 = xr[0], e1 = xr[1], e2 = xr[2], e3 = xr[3];
            const float a31_0 = P0 + bb31_0, a31_1 = P1 + bb31_1;
            const float a32_0 = P2 + bb32_0, a32_1 = P3 + bb32_1;
            const float s0 = 4.0f / (1.0f + __expf(-a32_0));
            const float s1 = 4.0f / (1.0f + __expf(-a32_1));
            const float px = fmaf(e0, sd0, m0);
            const float py = fmaf(e1, sd1, m1);
            const float th = fmaf(e2, sd2, m2);
            const float v  = fmaf(e3, sd3, m3);
            float sn, cs; __sincosf(th, &sn, &cs);
            const float dx = px - OBS_X, dy = py - OBS_Y;
            const float barrier     = dx * dx + dy * dy - RADIUS * RADIUS;
            const float barrier_dot = 2.f * dx * v * cs + 2.f * dy * v * sn;
            const float Lf2b = 2.f * v * v;
            const float G0 = 2.f * dx * v * sn - 2.f * dy * v * cs;   // -LgLfbu1
            const float G1 = -(2.f * dx * cs + 2.f * dy * sn);        // -LgLfbu2
            const float h  = Lf2b + (s0 + s1) * barrier_dot + s0 * s1 * barrier;
            const float u00 = -a31_0, u01 = -a31_1;
            const float viol = G0 * u00 + G1 * u01 - h;
            const float gg   = G0 * G0 + G1 * G1;
            const float lam  = fmaxf(viol, 0.f) / (gg + 1e-12f);
            float2 uo = make_float2(fmaf(-lam, G0, u00), fmaf(-lam, G1, u01));
            ((float2*)out)[row] = uo;
        }
    }
}

extern "C" void kernel_launch(void* const* d_in, const int* in_sizes, int n_in,
                              void* d_out, int out_size, void* d_ws, size_t ws_size,
                              hipStream_t stream) {
    const float* x     = (const float*)d_in[0];
    // d_in[1] = sgn (unused by the reference computation)
    const float* mean_ = (const float*)d_in[2];
    const float* std_  = (const float*)d_in[3];
    const float* w1    = (const float*)d_in[4];
    const float* b1    = (const float*)d_in[5];
    const float* w21   = (const float*)d_in[6];
    const float* b21   = (const float*)d_in[7];
    const float* w22   = (const float*)d_in[8];
    const float* b22   = (const float*)d_in[9];
    const float* w31   = (const float*)d_in[10];
    const float* b31   = (const float*)d_in[11];
    const float* w32   = (const float*)d_in[12];
    const float* b32   = (const float*)d_in[13];

    barriernet_fused<<<GRID, 256, 0, stream>>>(
        x, mean_, std_, w1, b1, w21, b21, w22, b22, w31, b31, w32, b32,
        (float*)d_out);
}